// Round 1
// 838.586 us; speedup vs baseline: 1.0228x; 1.0228x over previous
//
#include <hip/hip_runtime.h>
#include <math.h>

// Problem constants: B=64, D=512, H=HID=512 -> M = B*D = 32768, K = N = 512.
#define MM 32768
#define KK 512
#define NN 512
#define BM 128
#define BN 128
#define BK 32

typedef float  f32x4  __attribute__((ext_vector_type(4)));
typedef __bf16 bf16x8 __attribute__((ext_vector_type(8)));
typedef unsigned short u16x8 __attribute__((ext_vector_type(8)));
typedef unsigned short u16x4 __attribute__((ext_vector_type(4)));

__device__ __forceinline__ unsigned short f2bf(float f) {
    union { float f; unsigned int u; } v; v.f = f;
    unsigned int r = v.u + 0x7fffu + ((v.u >> 16) & 1u);  // round-to-nearest-even
    return (unsigned short)(r >> 16);
}

__device__ __forceinline__ float bf2f(unsigned short h) {
    union { unsigned int u; float f; } v; v.u = ((unsigned int)h) << 16;
    return v.f;
}

__device__ __forceinline__ void gl_lds16(const void* g, void* l) {
    __builtin_amdgcn_global_load_lds((const __attribute__((address_space(1))) void*)g,
                                     (__attribute__((address_space(3))) void*)l,
                                     16, 0, 0);
}

// ---------------------------------------------------------------------------
// fsum = fea1+fea2+fea3+fea4, cast to bf16.  8 elements / thread.
// ---------------------------------------------------------------------------
__global__ __launch_bounds__(256)
void fsum_cast(const float* __restrict__ f1, const float* __restrict__ f2,
               const float* __restrict__ f3, const float* __restrict__ f4,
               unsigned short* __restrict__ out)
{
    const long i = ((long)blockIdx.x * 256 + threadIdx.x) * 8;
    f32x4 s0 = *(const f32x4*)(f1 + i);
    f32x4 s1 = *(const f32x4*)(f1 + i + 4);
    s0 += *(const f32x4*)(f2 + i);  s1 += *(const f32x4*)(f2 + i + 4);
    s0 += *(const f32x4*)(f3 + i);  s1 += *(const f32x4*)(f3 + i + 4);
    s0 += *(const f32x4*)(f4 + i);  s1 += *(const f32x4*)(f4 + i + 4);
    u16x8 o;
    o[0] = f2bf(s0[0]); o[1] = f2bf(s0[1]); o[2] = f2bf(s0[2]); o[3] = f2bf(s0[3]);
    o[4] = f2bf(s1[0]); o[5] = f2bf(s1[1]); o[6] = f2bf(s1[2]); o[7] = f2bf(s1[3]);
    *(u16x8*)(out + i) = o;
}

// ---------------------------------------------------------------------------
// Weight prep:
//   z = 0     : Wgb[k][t]   = 0.25 * W_gcn[k][t]          (bf16 cast, NO transpose)
//   z = 1..4  : W1T[n][t]   = sum_b W1_i[b*512 + t][n]    (transpose + concat collapse)
//   z = 5..8  : W2T[n][k]   = W2_i[k][n]                  (transpose)
// ---------------------------------------------------------------------------
struct WArgs {
    const float* src[9];
    unsigned short* dst[9];
};

__global__ __launch_bounds__(256)
void wprep(WArgs a)
{
    __shared__ float t[32][33];
    const int z  = blockIdx.z;
    const float* __restrict__ src = a.src[z];
    unsigned short* __restrict__ dst = a.dst[z];
    const int k0 = blockIdx.x * 32;
    const int n0 = blockIdx.y * 32;
    const int tx = threadIdx.x;
    if (z == 0) {
        // straight 0.25x bf16 cast
        for (int kk = threadIdx.y; kk < 32; kk += 8) {
            float v = src[(long)(k0 + kk) * 512 + n0 + tx];
            dst[(long)(k0 + kk) * 512 + n0 + tx] = f2bf(0.25f * v);
        }
        return;
    }
    for (int kk = threadIdx.y; kk < 32; kk += 8) {
        float v = src[(long)(k0 + kk) * 512 + n0 + tx];
        if (z >= 1 && z <= 4) {
            v += src[(long)(512  + k0 + kk) * 512 + n0 + tx];
            v += src[(long)(1024 + k0 + kk) * 512 + n0 + tx];
            v += src[(long)(1536 + k0 + kk) * 512 + n0 + tx];
        }
        t[kk][tx] = v;
    }
    __syncthreads();
    for (int nn = threadIdx.y; nn < 32; nn += 8) {
        dst[(long)(n0 + nn) * 512 + k0 + tx] = f2bf(t[tx][nn]);
    }
}

// ---------------------------------------------------------------------------
// bcomb_z[n] = sum_t b_gcn[t] * W1T_z[n][t] + b1_z[n]     (runs after wprep)
// ---------------------------------------------------------------------------
struct BArgs {
    const unsigned short* w1t[4];
    const float* b1[4];
    float* out[4];
};

__global__ __launch_bounds__(256)
void bprep(const float* __restrict__ bg, BArgs a)
{
    __shared__ float bgs[512];
    const int z = blockIdx.x;
    const int tid = threadIdx.x;
    bgs[tid]       = bg[tid];
    bgs[tid + 256] = bg[tid + 256];
    __syncthreads();
    const unsigned short* __restrict__ w = a.w1t[z];
    for (int n = tid; n < 512; n += 256) {
        float acc = 0.0f;
        const unsigned short* row = w + (long)n * 512;
        #pragma unroll 4
        for (int t = 0; t < 512; t += 8) {
            u16x8 wv = *(const u16x8*)(row + t);
            #pragma unroll
            for (int jj = 0; jj < 8; ++jj) acc += bgs[t + jj] * bf2f(wv[jj]);
        }
        a.out[z][n] = acc + a.b1[z][n];
    }
}

// ---------------------------------------------------------------------------
// GEMM: C(M x N) = A(M x K, bf16) @ Bt(N x K, bf16)^T, + epilogue, batched over z.
// MODE 1: store bf16(relu(v + bias))         (h stage)
// MODE 2: store fp32 sigmoid(v + bias)*fea   (output stage)
// MODE 3: store bf16(v), no bias             (composed-weight stage)
// 128x128 tile, BK=32, 4 waves (2x2), double-buffered LDS with 1-barrier
// prefetch loop (stage next K-tile before current MFMAs, vmcnt drained by the
// single __syncthreads per iteration).
// MFMA operands SWAPPED (mfma(bfr, afr)): per m89 C/D layout, thread then holds
// row = lane&15 (M side), cols = (lane>>4)*4 + reg (4 consecutive N) ->
// fully vectorized epilogue (f32x4 / u16x4 per fragment).
// ---------------------------------------------------------------------------
struct GArgs {
    const unsigned short* A[4];
    const unsigned short* Bt[4];
    const float* bias[4];
    const float* fea[4];
    void* out[4];
};

__device__ __forceinline__ void stage4(const unsigned short* gb, unsigned short* lb, int r) {
    #pragma unroll
    for (int c = 0; c < 4; ++c)
        gl_lds16(gb + (long)(c * 16 + r) * KK, lb + c * 16 * BK);
}

template<int MODE>
__global__ __launch_bounds__(256)
void gemm_ep(GArgs a)
{
    __shared__ unsigned short As[2][BM * BK];   // 2 x 8 KB
    __shared__ unsigned short Bs[2][BN * BK];   // 2 x 8 KB

    const int z = blockIdx.z;
    const unsigned short* __restrict__ A  = a.A[z];
    const unsigned short* __restrict__ Bt = a.Bt[z];
    const float* __restrict__ bias = a.bias[z];
    const float* __restrict__ fea  = a.fea[z];
    void* __restrict__ out = a.out[z];

    const int tid  = threadIdx.x;
    const int lane = tid & 63;
    const int wave = tid >> 6;
    const int m0 = blockIdx.x * BM;
    const int n0 = blockIdx.y * BN;

    // staging role (wave-uniform): waves 0/1 stage A rows 0-63/64-127, waves 2/3 Bt.
    const bool isA = (wave < 2);
    const int rowbase = (wave & 1) * 64;
    const unsigned short* gsrc = isA ? A : Bt;
    const int r  = lane >> 2;   // 0..15 : row within 16-row chunk
    const int cb = lane & 3;    // 0..3  : 16B segment within 64B row
    const long grow0 = (isA ? (long)m0 : (long)n0) + rowbase;
    const unsigned short* gbase0 = gsrc + grow0 * KK + cb * 8;
    unsigned short* lb0 = (isA ? As[0] : Bs[0]) + rowbase * BK;
    unsigned short* lb1 = (isA ? As[1] : Bs[1]) + rowbase * BK;

    // fragment geometry: frag[idx = lane&15][k = (lane>>4)*8 + j]
    const int frow = lane & 15;
    const int fk   = (lane >> 4) * 8;
    const int wrow = wave >> 1;
    const int wcol = wave & 1;

    f32x4 acc[4][4] = {};

    stage4(gbase0, lb0, r);
    __syncthreads();   // drain prologue staging

    #pragma unroll 2
    for (int ks = 0; ks < KK / BK; ++ks) {
        const bool odd = (ks & 1);
        if (ks + 1 < KK / BK)
            stage4(gbase0 + (ks + 1) * BK, odd ? lb0 : lb1, r);   // prefetch next tile

        const unsigned short* Asc = odd ? As[1] : As[0];
        const unsigned short* Bsc = odd ? Bs[1] : Bs[0];
        bf16x8 afr[4], bfr[4];
        #pragma unroll
        for (int i = 0; i < 4; ++i)
            afr[i] = *(const bf16x8*)(Asc + (wrow * 64 + i * 16 + frow) * BK + fk);
        #pragma unroll
        for (int j = 0; j < 4; ++j)
            bfr[j] = *(const bf16x8*)(Bsc + (wcol * 64 + j * 16 + frow) * BK + fk);

        #pragma unroll
        for (int i = 0; i < 4; ++i)
            #pragma unroll
            for (int j = 0; j < 4; ++j)
                acc[i][j] = __builtin_amdgcn_mfma_f32_16x16x32_bf16(
                    bfr[j], afr[i], acc[i][j], 0, 0, 0);   // swapped operands

        __syncthreads();   // drains vmcnt(0) for prefetch + protects both buffers
    }

    // epilogue: swapped C/D layout -> row = lane&15, cols = (lane>>4)*4 + 0..3
    const int mr  = lane & 15;
    const int cq4 = (lane >> 4) * 4;
    #pragma unroll
    for (int j = 0; j < 4; ++j) {
        const int col = n0 + wcol * 64 + j * 16 + cq4;
        f32x4 bv;
        if (MODE == 3) { bv[0] = bv[1] = bv[2] = bv[3] = 0.0f; }
        else           { bv = *(const f32x4*)(bias + col); }
        #pragma unroll
        for (int i = 0; i < 4; ++i) {
            const long row = m0 + wrow * 64 + i * 16 + mr;
            f32x4 v = acc[i][j] + bv;
            if (MODE == 1) {
                u16x4 o;
                o[0] = f2bf(fmaxf(v[0], 0.0f)); o[1] = f2bf(fmaxf(v[1], 0.0f));
                o[2] = f2bf(fmaxf(v[2], 0.0f)); o[3] = f2bf(fmaxf(v[3], 0.0f));
                *(u16x4*)((unsigned short*)out + row * NN + col) = o;
            } else if (MODE == 3) {
                u16x4 o;
                o[0] = f2bf(v[0]); o[1] = f2bf(v[1]);
                o[2] = f2bf(v[2]); o[3] = f2bf(v[3]);
                *(u16x4*)((unsigned short*)out + row * NN + col) = o;
            } else {  // MODE 2: sigmoid gate * fea, fp32 out
                f32x4 fv = *(const f32x4*)(fea + row * NN + col);
                f32x4 o;
                #pragma unroll
                for (int q = 0; q < 4; ++q) {
                    float e = __expf(-v[q]);
                    o[q] = __fdividef(fv[q], 1.0f + e);
                }
                *(f32x4*)((float*)out + row * NN + col) = o;
            }
        }
    }
}

// ---------------------------------------------------------------------------
extern "C" void kernel_launch(void* const* d_in, const int* in_sizes, int n_in,
                              void* d_out, int out_size, void* d_ws, size_t ws_size,
                              hipStream_t stream)
{
    (void)in_sizes; (void)n_in; (void)out_size; (void)ws_size;

    const float* fea[4] = {(const float*)d_in[0], (const float*)d_in[1],
                           (const float*)d_in[2], (const float*)d_in[3]};
    const float* W_gcn = (const float*)d_in[4];
    const float* b_gcn = (const float*)d_in[5];
    const float *W1[4], *b1[4], *W2[4], *b2[4];
    for (int i = 0; i < 4; ++i) {
        W1[i] = (const float*)d_in[6 + 4 * i];
        b1[i] = (const float*)d_in[7 + 4 * i];
        W2[i] = (const float*)d_in[8 + 4 * i];
        b2[i] = (const float*)d_in[9 + 4 * i];
    }

    // workspace layout (MiB offsets):
    //   [0,32)    fsum (bf16, 32768x512)
    //   [32,36.5) 9 bf16 weight mats: Wgb, W1T[0..3], W2T[0..3]  (512x512 each)
    //   [40,42)   WcombT[0..3] (bf16 512x512 each)
    //   [44,..)   bcomb (4 x 512 f32)
    //   [48,176)  h[0..3] (bf16 32768x512 each, 32 MiB apart)
    const size_t MB = 1024 * 1024;
    char* ws = (char*)d_ws;
    unsigned short* fsum_h = (unsigned short*)ws;
    unsigned short* wbuf   = (unsigned short*)(ws + 32 * MB);
    unsigned short* Wgb = wbuf;
    unsigned short *W1T[4], *W2T[4], *WcT[4], *hbuf[4];
    for (int i = 0; i < 4; ++i) {
        W1T[i] = wbuf + (size_t)(1 + i) * 262144;
        W2T[i] = wbuf + (size_t)(5 + i) * 262144;
        WcT[i] = (unsigned short*)(ws + 40 * MB) + (size_t)i * 262144;
        hbuf[i] = (unsigned short*)(ws + 48 * MB + (size_t)i * 32 * MB);
    }
    float* bcomb = (float*)(ws + 44 * MB);

    fsum_cast<<<8192, 256, 0, stream>>>(fea[0], fea[1], fea[2], fea[3], fsum_h);

    WArgs wa;
    wa.src[0] = W_gcn; wa.dst[0] = Wgb;
    for (int i = 0; i < 4; ++i) { wa.src[1 + i] = W1[i]; wa.dst[1 + i] = W1T[i]; }
    for (int i = 0; i < 4; ++i) { wa.src[5 + i] = W2[i]; wa.dst[5 + i] = W2T[i]; }
    wprep<<<dim3(16, 16, 9), dim3(32, 8), 0, stream>>>(wa);

    BArgs ba;
    for (int i = 0; i < 4; ++i) { ba.w1t[i] = W1T[i]; ba.b1[i] = b1[i]; ba.out[i] = bcomb + (size_t)i * 512; }
    bprep<<<4, 256, 0, stream>>>(b_gcn, ba);

    // WcombT_z[n][k] = sum_t W1T_z[n][t] * (0.25*Wg[k][t])   (512x512x512 MFMA GEMM)
    GArgs g3;
    for (int i = 0; i < 4; ++i) {
        g3.A[i] = W1T[i]; g3.Bt[i] = Wgb; g3.bias[i] = nullptr;
        g3.fea[i] = nullptr; g3.out[i] = WcT[i];
    }
    gemm_ep<3><<<dim3(4, 4, 4), 256, 0, stream>>>(g3);

    // h_z = relu(fsum @ WcombT_z^T + bcomb_z)
    GArgs g1;
    for (int i = 0; i < 4; ++i) {
        g1.A[i] = fsum_h; g1.Bt[i] = WcT[i]; g1.bias[i] = bcomb + (size_t)i * 512;
        g1.fea[i] = nullptr; g1.out[i] = hbuf[i];
    }
    gemm_ep<1><<<dim3(MM / BM, NN / BN, 4), 256, 0, stream>>>(g1);

    // out_z = sigmoid(h_z @ W2T_z^T + b2_z) * fea_z
    float* outp = (float*)d_out;
    GArgs g2;
    for (int i = 0; i < 4; ++i) {
        g2.A[i] = hbuf[i]; g2.Bt[i] = W2T[i]; g2.bias[i] = b2[i];
        g2.fea[i] = fea[i]; g2.out[i] = outp + (size_t)i * MM * NN;
    }
    gemm_ep<2><<<dim3(MM / BM, NN / BN, 4), 256, 0, stream>>>(g2);
}

// Round 2
// 828.922 us; speedup vs baseline: 1.0347x; 1.0117x over previous
//
#include <hip/hip_runtime.h>
#include <math.h>

// Problem constants: B=64, D=512, H=HID=512 -> M = B*D = 32768, K = N = 512.
#define MM 32768
#define KK 512
#define NN 512
#define BM 128
#define BN 128
#define BK 32
#define NT (KK / BK)   // 16 K-tiles

typedef float  f32x4  __attribute__((ext_vector_type(4)));
typedef __bf16 bf16x8 __attribute__((ext_vector_type(8)));
typedef unsigned short u16x8 __attribute__((ext_vector_type(8)));
typedef unsigned short u16x4 __attribute__((ext_vector_type(4)));

__device__ __forceinline__ unsigned short f2bf(float f) {
    union { float f; unsigned int u; } v; v.f = f;
    unsigned int r = v.u + 0x7fffu + ((v.u >> 16) & 1u);  // round-to-nearest-even
    return (unsigned short)(r >> 16);
}

__device__ __forceinline__ float bf2f(unsigned short h) {
    union { unsigned int u; float f; } v; v.u = ((unsigned int)h) << 16;
    return v.f;
}

__device__ __forceinline__ void gl_lds16(const void* g, void* l) {
    __builtin_amdgcn_global_load_lds((const __attribute__((address_space(1))) void*)g,
                                     (__attribute__((address_space(3))) void*)l,
                                     16, 0, 0);
}

// ---------------------------------------------------------------------------
// fsum = fea1+fea2+fea3+fea4, cast to bf16.  8 elements / thread.
// ---------------------------------------------------------------------------
__global__ __launch_bounds__(256)
void fsum_cast(const float* __restrict__ f1, const float* __restrict__ f2,
               const float* __restrict__ f3, const float* __restrict__ f4,
               unsigned short* __restrict__ out)
{
    const long i = ((long)blockIdx.x * 256 + threadIdx.x) * 8;
    f32x4 s0 = *(const f32x4*)(f1 + i);
    f32x4 s1 = *(const f32x4*)(f1 + i + 4);
    s0 += *(const f32x4*)(f2 + i);  s1 += *(const f32x4*)(f2 + i + 4);
    s0 += *(const f32x4*)(f3 + i);  s1 += *(const f32x4*)(f3 + i + 4);
    s0 += *(const f32x4*)(f4 + i);  s1 += *(const f32x4*)(f4 + i + 4);
    u16x8 o;
    o[0] = f2bf(s0[0]); o[1] = f2bf(s0[1]); o[2] = f2bf(s0[2]); o[3] = f2bf(s0[3]);
    o[4] = f2bf(s1[0]); o[5] = f2bf(s1[1]); o[6] = f2bf(s1[2]); o[7] = f2bf(s1[3]);
    *(u16x8*)(out + i) = o;
}

// ---------------------------------------------------------------------------
// Weight prep:
//   z = 0     : Wgb[k][t]   = 0.25 * W_gcn[k][t]          (bf16 cast, NO transpose)
//   z = 1..4  : W1T[n][t]   = sum_b W1_i[b*512 + t][n]    (transpose + concat collapse)
//   z = 5..8  : W2T[n][k]   = W2_i[k][n]                  (transpose)
// ---------------------------------------------------------------------------
struct WArgs {
    const float* src[9];
    unsigned short* dst[9];
};

__global__ __launch_bounds__(256)
void wprep(WArgs a)
{
    __shared__ float t[32][33];
    const int z  = blockIdx.z;
    const float* __restrict__ src = a.src[z];
    unsigned short* __restrict__ dst = a.dst[z];
    const int k0 = blockIdx.x * 32;
    const int n0 = blockIdx.y * 32;
    const int tx = threadIdx.x;
    if (z == 0) {
        // straight 0.25x bf16 cast
        for (int kk = threadIdx.y; kk < 32; kk += 8) {
            float v = src[(long)(k0 + kk) * 512 + n0 + tx];
            dst[(long)(k0 + kk) * 512 + n0 + tx] = f2bf(0.25f * v);
        }
        return;
    }
    for (int kk = threadIdx.y; kk < 32; kk += 8) {
        float v = src[(long)(k0 + kk) * 512 + n0 + tx];
        if (z >= 1 && z <= 4) {
            v += src[(long)(512  + k0 + kk) * 512 + n0 + tx];
            v += src[(long)(1024 + k0 + kk) * 512 + n0 + tx];
            v += src[(long)(1536 + k0 + kk) * 512 + n0 + tx];
        }
        t[kk][tx] = v;
    }
    __syncthreads();
    for (int nn = threadIdx.y; nn < 32; nn += 8) {
        dst[(long)(n0 + nn) * 512 + k0 + tx] = f2bf(t[tx][nn]);
    }
}

// ---------------------------------------------------------------------------
// bcomb_z[n] = sum_t b_gcn[t] * W1T_z[n][t] + b1_z[n]     (runs after wprep)
// ---------------------------------------------------------------------------
struct BArgs {
    const unsigned short* w1t[4];
    const float* b1[4];
    float* out[4];
};

__global__ __launch_bounds__(256)
void bprep(const float* __restrict__ bg, BArgs a)
{
    __shared__ float bgs[512];
    const int z = blockIdx.x;
    const int tid = threadIdx.x;
    bgs[tid]       = bg[tid];
    bgs[tid + 256] = bg[tid + 256];
    __syncthreads();
    const unsigned short* __restrict__ w = a.w1t[z];
    for (int n = tid; n < 512; n += 256) {
        float acc = 0.0f;
        const unsigned short* row = w + (long)n * 512;
        #pragma unroll 4
        for (int t = 0; t < 512; t += 8) {
            u16x8 wv = *(const u16x8*)(row + t);
            #pragma unroll
            for (int jj = 0; jj < 8; ++jj) acc += bgs[t + jj] * bf2f(wv[jj]);
        }
        a.out[z][n] = acc + a.b1[z][n];
    }
}

// ---------------------------------------------------------------------------
// GEMM: C(M x N) = A(M x K, bf16) @ Bt(N x K, bf16)^T, + epilogue, batched over z.
// MODE 1: store bf16(relu(v + bias))         (h stage)
// MODE 2: store fp32 sigmoid(v + bias)*fea   (output stage)
// MODE 3: store bf16(v), no bias             (composed-weight stage)
//
// 128x128 tile, BK=32, 4 waves (2x2), 3-deep LDS pipeline with COUNTED vmcnt
// (T3/T4): loads for 2 future K-tiles stay in flight across raw s_barriers;
// never vmcnt(0) in the steady-state loop.
//
// LDS K-segment XOR-swizzle (T2, both-sides): global source segment is
// pre-swizzled (cb ^ (r>>1)&3), LDS dest stays linear (global_load_lds
// requirement), fragment read un-swizzles (seg = (lane>>4) ^ (frow>>1)&3).
// Rows 0..15 then hit bank-groups 2-way instead of 8-way (free per m136).
//
// MFMA operands SWAPPED (mfma(bfr, afr)): per m89 C/D layout, thread holds
// row = lane&15 (M side), cols = (lane>>4)*4 + reg (4 consecutive N) ->
// fully vectorized epilogue (f32x4 / u16x4 per fragment).
// ---------------------------------------------------------------------------
struct GArgs {
    const unsigned short* A[4];
    const unsigned short* Bt[4];
    const float* bias[4];
    const float* fea[4];
    void* out[4];
};

__device__ __forceinline__ void stage4(const unsigned short* gb, unsigned short* lb, int r) {
    #pragma unroll
    for (int c = 0; c < 4; ++c)
        gl_lds16(gb + (long)(c * 16 + r) * KK, lb + c * 16 * BK);
}

template<int MODE>
__global__ __launch_bounds__(256)
void gemm_ep(GArgs a)
{
    __shared__ __attribute__((aligned(16))) unsigned short As[3][BM * BK];  // 3 x 8 KB
    __shared__ __attribute__((aligned(16))) unsigned short Bs[3][BN * BK];  // 3 x 8 KB

    const int z = blockIdx.z;
    const unsigned short* __restrict__ A  = a.A[z];
    const unsigned short* __restrict__ Bt = a.Bt[z];
    const float* __restrict__ bias = a.bias[z];
    const float* __restrict__ fea  = a.fea[z];
    void* __restrict__ out = a.out[z];

    const int tid  = threadIdx.x;
    const int lane = tid & 63;
    const int wave = tid >> 6;
    const int m0 = blockIdx.x * BM;
    const int n0 = blockIdx.y * BN;

    // staging role (wave-uniform): waves 0/1 stage A rows 0-63/64-127, waves 2/3 Bt.
    const bool isA = (wave < 2);
    const int rowbase = (wave & 1) * 64;
    const unsigned short* gsrc = isA ? A : Bt;
    const int r   = lane >> 2;                  // 0..15 : row within 16-row chunk
    const int cb  = lane & 3;                   // 0..3  : 16B segment within 64B row
    const int cbs = cb ^ ((r >> 1) & 3);        // pre-swizzled global segment
    const long grow0 = (isA ? (long)m0 : (long)n0) + rowbase;
    const unsigned short* gbase0 = gsrc + grow0 * KK + cbs * 8;
    unsigned short* lb[3] = {
        (isA ? As[0] : Bs[0]) + rowbase * BK,
        (isA ? As[1] : Bs[1]) + rowbase * BK,
        (isA ? As[2] : Bs[2]) + rowbase * BK };

    // fragment geometry: frag[idx = lane&15][k-seg = (lane>>4) ^ swz(frow)]
    const int frow = lane & 15;
    const int fk   = ((lane >> 4) ^ ((frow >> 1) & 3)) * 8;   // un-swizzled read
    const int wrow = wave >> 1;
    const int wcol = wave & 1;

    f32x4 acc[4][4] = {};

    // prologue: fill the 3-deep pipe (12 loads in flight per wave)
    stage4(gbase0 + 0 * BK, lb[0], r);
    stage4(gbase0 + 1 * BK, lb[1], r);
    stage4(gbase0 + 2 * BK, lb[2], r);

    #pragma unroll
    for (int ks = 0; ks < NT; ++ks) {
        // wait until the OLDEST tile's 4 loads have landed; keep the rest in flight
        if      (ks < NT - 2) asm volatile("s_waitcnt vmcnt(8)" ::: "memory");
        else if (ks == NT - 2) asm volatile("s_waitcnt vmcnt(4)" ::: "memory");
        else                   asm volatile("s_waitcnt vmcnt(0)" ::: "memory");
        __builtin_amdgcn_s_barrier();            // everyone's tile-ks loads landed
        asm volatile("" ::: "memory");

        const unsigned short* Asc = As[ks % 3];
        const unsigned short* Bsc = Bs[ks % 3];
        bf16x8 afr[4], bfr[4];
        #pragma unroll
        for (int i = 0; i < 4; ++i)
            afr[i] = *(const bf16x8*)(Asc + (wrow * 64 + i * 16 + frow) * BK + fk);
        #pragma unroll
        for (int j = 0; j < 4; ++j)
            bfr[j] = *(const bf16x8*)(Bsc + (wcol * 64 + j * 16 + frow) * BK + fk);

        #pragma unroll
        for (int i = 0; i < 4; ++i)
            #pragma unroll
            for (int j = 0; j < 4; ++j)
                acc[i][j] = __builtin_amdgcn_mfma_f32_16x16x32_bf16(
                    bfr[j], afr[i], acc[i][j], 0, 0, 0);   // swapped operands

        asm volatile("" ::: "memory");
        __builtin_amdgcn_s_barrier();            // everyone done reading buf[ks%3]
        asm volatile("" ::: "memory");
        if (ks + 3 < NT)
            stage4(gbase0 + (ks + 3) * BK, lb[ks % 3], r);  // refill freed buffer
    }

    // epilogue: swapped C/D layout -> row = lane&15, cols = (lane>>4)*4 + 0..3
    const int mr  = lane & 15;
    const int cq4 = (lane >> 4) * 4;
    #pragma unroll
    for (int j = 0; j < 4; ++j) {
        const int col = n0 + wcol * 64 + j * 16 + cq4;
        f32x4 bv;
        if (MODE == 3) { bv[0] = bv[1] = bv[2] = bv[3] = 0.0f; }
        else           { bv = *(const f32x4*)(bias + col); }
        #pragma unroll
        for (int i = 0; i < 4; ++i) {
            const long row = m0 + wrow * 64 + i * 16 + mr;
            f32x4 v = acc[i][j] + bv;
            if (MODE == 1) {
                u16x4 o;
                o[0] = f2bf(fmaxf(v[0], 0.0f)); o[1] = f2bf(fmaxf(v[1], 0.0f));
                o[2] = f2bf(fmaxf(v[2], 0.0f)); o[3] = f2bf(fmaxf(v[3], 0.0f));
                *(u16x4*)((unsigned short*)out + row * NN + col) = o;
            } else if (MODE == 3) {
                u16x4 o;
                o[0] = f2bf(v[0]); o[1] = f2bf(v[1]);
                o[2] = f2bf(v[2]); o[3] = f2bf(v[3]);
                *(u16x4*)((unsigned short*)out + row * NN + col) = o;
            } else {  // MODE 2: sigmoid gate * fea, fp32 out
                f32x4 fv = *(const f32x4*)(fea + row * NN + col);
                f32x4 o;
                #pragma unroll
                for (int q = 0; q < 4; ++q) {
                    float e = __expf(-v[q]);
                    o[q] = __fdividef(fv[q], 1.0f + e);
                }
                *(f32x4*)((float*)out + row * NN + col) = o;
            }
        }
    }
}

// ---------------------------------------------------------------------------
extern "C" void kernel_launch(void* const* d_in, const int* in_sizes, int n_in,
                              void* d_out, int out_size, void* d_ws, size_t ws_size,
                              hipStream_t stream)
{
    (void)in_sizes; (void)n_in; (void)out_size; (void)ws_size;

    const float* fea[4] = {(const float*)d_in[0], (const float*)d_in[1],
                           (const float*)d_in[2], (const float*)d_in[3]};
    const float* W_gcn = (const float*)d_in[4];
    const float* b_gcn = (const float*)d_in[5];
    const float *W1[4], *b1[4], *W2[4], *b2[4];
    for (int i = 0; i < 4; ++i) {
        W1[i] = (const float*)d_in[6 + 4 * i];
        b1[i] = (const float*)d_in[7 + 4 * i];
        W2[i] = (const float*)d_in[8 + 4 * i];
        b2[i] = (const float*)d_in[9 + 4 * i];
    }

    // workspace layout (MiB offsets):
    //   [0,32)    fsum (bf16, 32768x512)
    //   [32,36.5) 9 bf16 weight mats: Wgb, W1T[0..3], W2T[0..3]  (512x512 each)
    //   [40,42)   WcombT[0..3] (bf16 512x512 each)
    //   [44,..)   bcomb (4 x 512 f32)
    //   [48,176)  h[0..3] (bf16 32768x512 each, 32 MiB apart)
    const size_t MB = 1024 * 1024;
    char* ws = (char*)d_ws;
    unsigned short* fsum_h = (unsigned short*)ws;
    unsigned short* wbuf   = (unsigned short*)(ws + 32 * MB);
    unsigned short* Wgb = wbuf;
    unsigned short *W1T[4], *W2T[4], *WcT[4], *hbuf[4];
    for (int i = 0; i < 4; ++i) {
        W1T[i] = wbuf + (size_t)(1 + i) * 262144;
        W2T[i] = wbuf + (size_t)(5 + i) * 262144;
        WcT[i] = (unsigned short*)(ws + 40 * MB) + (size_t)i * 262144;
        hbuf[i] = (unsigned short*)(ws + 48 * MB + (size_t)i * 32 * MB);
    }
    float* bcomb = (float*)(ws + 44 * MB);

    fsum_cast<<<8192, 256, 0, stream>>>(fea[0], fea[1], fea[2], fea[3], fsum_h);

    WArgs wa;
    wa.src[0] = W_gcn; wa.dst[0] = Wgb;
    for (int i = 0; i < 4; ++i) { wa.src[1 + i] = W1[i]; wa.dst[1 + i] = W1T[i]; }
    for (int i = 0; i < 4; ++i) { wa.src[5 + i] = W2[i]; wa.dst[5 + i] = W2T[i]; }
    wprep<<<dim3(16, 16, 9), dim3(32, 8), 0, stream>>>(wa);

    BArgs ba;
    for (int i = 0; i < 4; ++i) { ba.w1t[i] = W1T[i]; ba.b1[i] = b1[i]; ba.out[i] = bcomb + (size_t)i * 512; }
    bprep<<<4, 256, 0, stream>>>(b_gcn, ba);

    // WcombT_z[n][k] = sum_t W1T_z[n][t] * (0.25*Wg[k][t])   (512x512x512 MFMA GEMM)
    GArgs g3;
    for (int i = 0; i < 4; ++i) {
        g3.A[i] = W1T[i]; g3.Bt[i] = Wgb; g3.bias[i] = nullptr;
        g3.fea[i] = nullptr; g3.out[i] = WcT[i];
    }
    gemm_ep<3><<<dim3(4, 4, 4), 256, 0, stream>>>(g3);

    // h_z = relu(fsum @ WcombT_z^T + bcomb_z)
    GArgs g1;
    for (int i = 0; i < 4; ++i) {
        g1.A[i] = fsum_h; g1.Bt[i] = WcT[i]; g1.bias[i] = bcomb + (size_t)i * 512;
        g1.fea[i] = nullptr; g1.out[i] = hbuf[i];
    }
    gemm_ep<1><<<dim3(MM / BM, NN / BN, 4), 256, 0, stream>>>(g1);

    // out_z = sigmoid(h_z @ W2T_z^T + b2_z) * fea_z
    float* outp = (float*)d_out;
    GArgs g2;
    for (int i = 0; i < 4; ++i) {
        g2.A[i] = hbuf[i]; g2.Bt[i] = W2T[i]; g2.bias[i] = b2[i];
        g2.fea[i] = fea[i]; g2.out[i] = outp + (size_t)i * MM * NN;
    }
    gemm_ep<2><<<dim3(MM / BM, NN / BN, 4), 256, 0, stream>>>(g2);
}